// Round 5
// baseline (22.998 us; speedup 1.0000x reference)
//
#include <hip/hip_runtime.h>

// Dihedral2Coord — two-kernel split.
//
// K1 (scan): one wave per molecule. Quaternion affine prefix scan over the
//   128 LOCAL-frame step rotations (dihedrals are rigid-invariant so phi_k
//   comes from pos0 alone). Emits final atoms 0..131 and the cumulative map
//   P_127 (3x4 matrix, 3 float4 rows) to d_ws.
// K2 (tail): one block per molecule, pure streaming: out[m] = F(pos0[m]) for
//   atoms 132..511, coalesced 12B/lane scalar dword traffic.

#define NK 128
#define NM 512
#define NMOL 4096

struct Aff { float qw, qx, qy, qz, tx, ty, tz; };

__device__ __forceinline__ void qrot(float qw, float qx, float qy, float qz,
                                     float vx, float vy, float vz,
                                     float& ox, float& oy, float& oz) {
    // v' = v + 2*qv×(qv×v + qw*v)
    const float ux = qy*vz - qz*vy + qw*vx;
    const float uy = qz*vx - qx*vz + qw*vy;
    const float uz = qx*vy - qy*vx + qw*vz;
    ox = vx + 2.f*(qy*uz - qz*uy);
    oy = vy + 2.f*(qz*ux - qx*uz);
    oz = vz + 2.f*(qx*uy - qy*ux);
}

__device__ __forceinline__ Aff aff_compose(const Aff& Q, const Aff& P) {
    Aff r;
    r.qw = Q.qw*P.qw - Q.qx*P.qx - Q.qy*P.qy - Q.qz*P.qz;
    r.qx = Q.qw*P.qx + Q.qx*P.qw + Q.qy*P.qz - Q.qz*P.qy;
    r.qy = Q.qw*P.qy - Q.qx*P.qz + Q.qy*P.qw + Q.qz*P.qx;
    r.qz = Q.qw*P.qz + Q.qx*P.qy - Q.qy*P.qx + Q.qz*P.qw;
    float rx, ry, rz;
    qrot(Q.qw, Q.qx, Q.qy, Q.qz, P.tx, P.ty, P.tz, rx, ry, rz);
    r.tx = rx + Q.tx; r.ty = ry + Q.ty; r.tz = rz + Q.tz;
    return r;
}

__device__ __forceinline__ void qnorm(Aff& a) {
    const float r = rsqrtf(a.qw*a.qw + a.qx*a.qx + a.qy*a.qy + a.qz*a.qz);
    a.qw *= r; a.qx *= r; a.qy *= r; a.qz *= r;
}

__device__ __forceinline__ Aff build_B(const float* a, float th) {
    const float ijx=a[3]-a[0], ijy=a[4]-a[1],  ijz=a[5]-a[2];
    const float jkx=a[6]-a[3], jky=a[7]-a[4],  jkz=a[8]-a[5];
    const float klx=a[9]-a[6], kly=a[10]-a[7], klz=a[11]-a[8];
    const float n1x=ijy*jkz-ijz*jky, n1y=ijz*jkx-ijx*jkz, n1z=ijx*jky-ijy*jkx;
    const float n2x=jky*klz-jkz*kly, n2y=jkz*klx-jkx*klz, n2z=jkx*kly-jky*klx;
    const float mx =n1y*jkz-n1z*jky, my =n1z*jkx-n1x*jkz, mz =n1x*jky-n1y*jkx;
    const float dmn=mx*n2x+my*n2y+mz*n2z;
    const float dnn=n1x*n2x+n1y*n2y+n1z*n2z;
    const float Lm =mx*mx+my*my+mz*mz;
    const float L1 =n1x*n1x+n1y*n1y+n1z*n1z;
    const float L2 =n2x*n2x+n2y*n2y+n2z*n2z;
    float sphi = dmn*rsqrtf(Lm*L2);
    float cphi = dnn*rsqrtf(L1*L2);
    const float rn = rsqrtf(sphi*sphi + cphi*cphi);
    sphi *= rn; cphi *= rn;
    float sth, cth; sincosf(th, &sth, &cth);
    const float c = cth*cphi - sth*sphi;   // cos(theta+phi)
    const float s = sth*cphi + cth*sphi;   // sin(theta+phi)
    const float Ljk = jkx*jkx + jky*jky + jkz*jkz;
    const float inva = rsqrtf(fmaxf(Ljk, 1e-24f));
    const float ax = jkx*inva, ay = jky*inva, az = jkz*inva;
    const float hc = sqrtf(fmaxf(0.f, 0.5f*(1.f + c)));
    const float hs = copysignf(sqrtf(fmaxf(0.f, 0.5f*(1.f - c))), s);
    Aff b;
    b.qw = hc; b.qx = hs*ax; b.qy = hs*ay; b.qz = hs*az;
    float rx, ry, rz;
    qrot(b.qw, b.qx, b.qy, b.qz, a[3], a[4], a[5], rx, ry, rz);
    b.tx = a[3] - rx; b.ty = a[4] - ry; b.tz = a[5] - rz;
    return b;
}

#define SHFL_AFF_UP(D, S, off)                                           \
    D.qw = __shfl_up(S.qw, off, 64); D.qx = __shfl_up(S.qx, off, 64);    \
    D.qy = __shfl_up(S.qy, off, 64); D.qz = __shfl_up(S.qz, off, 64);    \
    D.tx = __shfl_up(S.tx, off, 64); D.ty = __shfl_up(S.ty, off, 64);    \
    D.tz = __shfl_up(S.tz, off, 64);

// ---------------- kernel 1: scan + head (atoms 0..131) + F to ws ----------
__global__ __launch_bounds__(64) void dihedral_scan_head_kernel(
    const float* __restrict__ theta,  // (NMOL, NK)
    const float* __restrict__ pos0,   // (NMOL, NM, 3)
    float* __restrict__ out,          // (NMOL, NM, 3)
    float* __restrict__ ws)           // (NMOL, 12)  P_127 matrix rows
{
    const int lane = threadIdx.x;
    const int mol  = blockIdx.x;
    const float4* __restrict__ pb4 = (const float4*)(pos0 + (size_t)mol * (NM*3));
    float4*       __restrict__ ob4 = (float4*)(out  + (size_t)mol * (NM*3));

    __shared__ float sA[400];   // pos0 atoms 0..131 (396 used)
    __shared__ float sO[400];   // final atoms 0..131

    float4* sA4 = (float4*)sA;
    sA4[lane] = pb4[lane];
    if (lane < 35) sA4[64 + lane] = pb4[64 + lane];
    const float2 th2 = ((const float2*)(theta + (size_t)mol * NK))[lane];
    __syncthreads();

    // lane k handles steps 2k, 2k+1 (atoms 2k..2k+4)
    float A[15];
    const float* ap = &sA[lane * 6];
    #pragma unroll
    for (int i = 0; i < 15; ++i) A[i] = ap[i];

    Aff Bev = build_B(&A[0], th2.x);
    Aff Bod = build_B(&A[3], th2.y);
    Aff S   = aff_compose(Bev, Bod);

    #pragma unroll
    for (int off = 1; off < 64; off <<= 1) {
        Aff Q; SHFL_AFF_UP(Q, S, off);
        if (lane >= off) S = aff_compose(Q, S);
    }
    Aff E; SHFL_AFF_UP(E, S, 1);
    if (lane == 0) { E.qw = 1.f; E.qx = E.qy = E.qz = 0.f; E.tx = E.ty = E.tz = 0.f; }
    Aff Pe = aff_compose(E, Bev);
    qnorm(Pe); qnorm(S);

    {   // atoms 2k+3 (P_{2k}) and 2k+4 (P_{2k+1})
        float ox, oy, oz;
        float* op = &sO[lane * 6 + 9];
        qrot(Pe.qw, Pe.qx, Pe.qy, Pe.qz, A[9], A[10], A[11], ox, oy, oz);
        op[0] = ox + Pe.tx; op[1] = oy + Pe.ty; op[2] = oz + Pe.tz;
        qrot(S.qw, S.qx, S.qy, S.qz, A[12], A[13], A[14], ox, oy, oz);
        op[3] = ox + S.tx;  op[4] = oy + S.ty;  op[5] = oz + S.tz;
    }
    if (lane < 9) sO[lane] = sA[lane];   // atoms 0..2 never move
    if (lane == 63) {
        // atom 131 = P_127(pos0[131])
        float ox, oy, oz;
        qrot(S.qw, S.qx, S.qy, S.qz, sA[393], sA[394], sA[395], ox, oy, oz);
        sO[393] = ox + S.tx; sO[394] = oy + S.ty; sO[395] = oz + S.tz;
        // F = P_127 as 3x4 matrix rows -> ws
        const float qw=S.qw, qx=S.qx, qy=S.qy, qz=S.qz;
        float4 r0, r1, r2;
        r0.x = 1.f - 2.f*(qy*qy + qz*qz);
        r0.y = 2.f*(qx*qy - qw*qz);
        r0.z = 2.f*(qx*qz + qw*qy);
        r0.w = S.tx;
        r1.x = 2.f*(qx*qy + qw*qz);
        r1.y = 1.f - 2.f*(qx*qx + qz*qz);
        r1.z = 2.f*(qy*qz - qw*qx);
        r1.w = S.ty;
        r2.x = 2.f*(qx*qz - qw*qy);
        r2.y = 2.f*(qy*qz + qw*qx);
        r2.z = 1.f - 2.f*(qx*qx + qy*qy);
        r2.w = S.tz;
        float4* wp = (float4*)(ws + (size_t)mol * 12);
        wp[0] = r0; wp[1] = r1; wp[2] = r2;
    }
    __syncthreads();

    const float4* sO4 = (const float4*)sO;
    ob4[lane] = sO4[lane];
    if (lane < 35) ob4[64 + lane] = sO4[64 + lane];
}

// ---------------- kernel 2: tail atoms 132..511, pure streaming ----------
#define K2_TPB 384
__global__ __launch_bounds__(K2_TPB) void dihedral_tail_kernel(
    const float* __restrict__ pos0,   // (NMOL, NM, 3)
    const float* __restrict__ ws,     // (NMOL, 12)
    float* __restrict__ out)          // (NMOL, NM, 3)
{
    const int t   = threadIdx.x;
    const int mol = blockIdx.x;
    const float4* __restrict__ wp = (const float4*)(ws + (size_t)mol * 12);
    const float4 r0 = wp[0], r1 = wp[1], r2 = wp[2];

    if (t < NM - (NK + 3) - 1) {  // 380 tail atoms: 132..511
        const int m = (NK + 4) + t;
        const float* p = pos0 + (size_t)mol * (NM*3) + (size_t)m * 3;
        float*       o = out  + (size_t)mol * (NM*3) + (size_t)m * 3;
        const float x = p[0], y = p[1], z = p[2];
        o[0] = r0.x*x + r0.y*y + r0.z*z + r0.w;
        o[1] = r1.x*x + r1.y*y + r1.z*z + r1.w;
        o[2] = r2.x*x + r2.y*y + r2.z*z + r2.w;
    } else if (t == NM - (NK + 3) - 1) {
        // atom 132 (kernel1 covered only through 131)
        const int m = NK + 4 - 1;
        const float* p = pos0 + (size_t)mol * (NM*3) + (size_t)m * 3;
        float*       o = out  + (size_t)mol * (NM*3) + (size_t)m * 3;
        const float x = p[0], y = p[1], z = p[2];
        o[0] = r0.x*x + r0.y*y + r0.z*z + r0.w;
        o[1] = r1.x*x + r1.y*y + r1.z*z + r1.w;
        o[2] = r2.x*x + r2.y*y + r2.z*z + r2.w;
    }
}

extern "C" void kernel_launch(void* const* d_in, const int* in_sizes, int n_in,
                              void* d_out, int out_size, void* d_ws, size_t ws_size,
                              hipStream_t stream) {
    const float* theta = (const float*)d_in[0];  // input (N,K) fp32
    const float* pos0  = (const float*)d_in[1];  // pos0 (N,M,3) fp32
    float* out = (float*)d_out;                  // (N,M,3) fp32
    float* ws  = (float*)d_ws;                   // (N,12) scratch
    dihedral_scan_head_kernel<<<NMOL, 64, 0, stream>>>(theta, pos0, out, ws);
    dihedral_tail_kernel<<<NMOL, K2_TPB, 0, stream>>>(pos0, ws, out);
}

// Round 6
// 19.013 us; speedup vs baseline: 1.2096x; 1.2096x over previous
//
#include <hip/hip_runtime.h>

// Dihedral2Coord — single fused kernel, one molecule per WAVE, no barriers.
//
// final[m] = P_{m-3}(pos0[m]); P_k = B_0∘...∘B_k where B_k is the LOCAL-frame
// step rotation (dihedrals are rigid-invariant so phi_k comes from pos0 only).
// Lane k of the wave owns steps 2k,2k+1. All LDS traffic is wave-private
// (per-wave slice), and DS ops of one wave execute in order -> NO
// __syncthreads anywhere; the 4 waves of a block pipeline independently.

#define NK 128
#define NM 512
#define NMOL 4096
#define TPB 256
#define MPW 4     // molecules (waves) per block

struct Aff { float qw, qx, qy, qz, tx, ty, tz; };

__device__ __forceinline__ void qrot(float qw, float qx, float qy, float qz,
                                     float vx, float vy, float vz,
                                     float& ox, float& oy, float& oz) {
    // v' = v + 2*qv×(qv×v + qw*v)
    const float ux = qy*vz - qz*vy + qw*vx;
    const float uy = qz*vx - qx*vz + qw*vy;
    const float uz = qx*vy - qy*vx + qw*vz;
    ox = vx + 2.f*(qy*uz - qz*uy);
    oy = vy + 2.f*(qz*ux - qx*uz);
    oz = vz + 2.f*(qx*uy - qy*ux);
}

__device__ __forceinline__ Aff aff_compose(const Aff& Q, const Aff& P) {
    Aff r;
    r.qw = Q.qw*P.qw - Q.qx*P.qx - Q.qy*P.qy - Q.qz*P.qz;
    r.qx = Q.qw*P.qx + Q.qx*P.qw + Q.qy*P.qz - Q.qz*P.qy;
    r.qy = Q.qw*P.qy - Q.qx*P.qz + Q.qy*P.qw + Q.qz*P.qx;
    r.qz = Q.qw*P.qz + Q.qx*P.qy - Q.qy*P.qx + Q.qz*P.qw;
    float rx, ry, rz;
    qrot(Q.qw, Q.qx, Q.qy, Q.qz, P.tx, P.ty, P.tz, rx, ry, rz);
    r.tx = rx + Q.tx; r.ty = ry + Q.ty; r.tz = rz + Q.tz;
    return r;
}

__device__ __forceinline__ void qnorm(Aff& a) {
    const float r = rsqrtf(a.qw*a.qw + a.qx*a.qx + a.qy*a.qy + a.qz*a.qz);
    a.qw *= r; a.qx *= r; a.qy *= r; a.qz *= r;
}

// B from (cos,sin) of total angle, unnormalized axis (ax,ay,az) with |axis|^2
// precomputed handling, pivot p.
__device__ __forceinline__ Aff make_step(float c, float s,
                                         float ax, float ay, float az,
                                         float px, float py, float pz) {
    const float hc = sqrtf(fmaxf(0.f, 0.5f*(1.f + c)));
    const float hs = copysignf(sqrtf(fmaxf(0.f, 0.5f*(1.f - c))), s);
    Aff b; b.qw = hc; b.qx = hs*ax; b.qy = hs*ay; b.qz = hs*az;
    float rx, ry, rz;
    qrot(b.qw, b.qx, b.qy, b.qz, px, py, pz, rx, ry, rz);
    b.tx = px - rx; b.ty = py - ry; b.tz = pz - rz;
    return b;
}

#define SHFL_AFF_UP(D, S, off)                                           \
    D.qw = __shfl_up(S.qw, off, 64); D.qx = __shfl_up(S.qx, off, 64);    \
    D.qy = __shfl_up(S.qy, off, 64); D.qz = __shfl_up(S.qz, off, 64);    \
    D.tx = __shfl_up(S.tx, off, 64); D.ty = __shfl_up(S.ty, off, 64);    \
    D.tz = __shfl_up(S.tz, off, 64);

__global__ __launch_bounds__(TPB, 4) void dihedral_fused_kernel(
    const float* __restrict__ theta,  // (NMOL, NK)
    const float* __restrict__ pos0,   // (NMOL, NM, 3)
    float* __restrict__ out)          // (NMOL, NM, 3)
{
    const int tid  = threadIdx.x;
    const int lane = tid & 63;
    const int wid  = tid >> 6;
    const int mol  = blockIdx.x * MPW + wid;
    const float4* __restrict__ pb4 = (const float4*)(pos0 + (size_t)mol * (NM*3));
    float4*       __restrict__ ob4 = (float4*)(out  + (size_t)mol * (NM*3));

    __shared__ float sA[MPW][400];   // per-wave: pos0 atoms 0..131
    __shared__ float sO[MPW][400];   // per-wave: final atoms 0..131

    // ---- issue ALL global loads up front ----
    float4 h0 = pb4[lane];
    float4 h1; if (lane < 35) h1 = pb4[64 + lane];
    const float2 th2 = ((const float2*)(theta + (size_t)mol * NK))[lane];
    float4 Ta0, Ta1, Ta2, Tb0, Tb1, Tb2;
    { const int b = 99 + 3*lane; Ta0 = pb4[b]; Ta1 = pb4[b+1]; Ta2 = pb4[b+2]; }
    const bool hasB = (lane < 31);   // tasks 64..94
    if (hasB) { const int b = 99 + 3*(64 + lane); Tb0 = pb4[b]; Tb1 = pb4[b+1]; Tb2 = pb4[b+2]; }

    // stage head into this wave's LDS slice (same-wave DS ordering, no barrier)
    float4* sA4 = (float4*)sA[wid];
    sA4[lane] = h0;
    if (lane < 35) sA4[64 + lane] = h1;

    // lane k: atoms 2k..2k+4 (15 floats, 8B-aligned)
    float A[16];
    const float2* ap2 = (const float2*)&sA[wid][lane * 6];
    #pragma unroll
    for (int i = 0; i < 7; ++i) { const float2 v = ap2[i]; A[2*i] = v.x; A[2*i+1] = v.y; }
    A[14] = sA[wid][lane * 6 + 14];

    // ---- dihedral geometry for steps 2k (even) and 2k+1 (odd), shared ----
    const float v01x=A[3]-A[0],  v01y=A[4]-A[1],   v01z=A[5]-A[2];
    const float v12x=A[6]-A[3],  v12y=A[7]-A[4],   v12z=A[8]-A[5];
    const float v23x=A[9]-A[6],  v23y=A[10]-A[7],  v23z=A[11]-A[8];
    const float v34x=A[12]-A[9], v34y=A[13]-A[10], v34z=A[14]-A[11];
    const float n1x=v01y*v12z-v01z*v12y, n1y=v01z*v12x-v01x*v12z, n1z=v01x*v12y-v01y*v12x;
    const float n2x=v12y*v23z-v12z*v23y, n2y=v12z*v23x-v12x*v23z, n2z=v12x*v23y-v12y*v23x;
    const float n3x=v23y*v34z-v23z*v34y, n3y=v23z*v34x-v23x*v34z, n3z=v23x*v34y-v23y*v34x;
    const float mex=n1y*v12z-n1z*v12y,  mey=n1z*v12x-n1x*v12z,  mez=n1x*v12y-n1y*v12x;
    const float mox=n2y*v23z-n2z*v23y,  moy=n2z*v23x-n2x*v23z,  moz=n2x*v23y-n2y*v23x;
    const float L1=n1x*n1x+n1y*n1y+n1z*n1z;
    const float L2=n2x*n2x+n2y*n2y+n2z*n2z;
    const float L3=n3x*n3x+n3y*n3y+n3z*n3z;
    const float Lme=mex*mex+mey*mey+mez*mez;
    const float Lmo=mox*mox+moy*moy+moz*moz;

    // even step 2k
    float sphE = (mex*n2x+mey*n2y+mez*n2z) * rsqrtf(Lme*L2);
    float cphE = (n1x*n2x+n1y*n2y+n1z*n2z) * rsqrtf(L1*L2);
    { const float rn = rsqrtf(sphE*sphE + cphE*cphE); sphE *= rn; cphE *= rn; }
    float sthE, cthE; sincosf(th2.x, &sthE, &cthE);
    const float cE = cthE*cphE - sthE*sphE;
    const float sE = sthE*cphE + cthE*sphE;
    const float LjkE = v12x*v12x+v12y*v12y+v12z*v12z;
    const float invE = rsqrtf(fmaxf(LjkE, 1e-24f));
    Aff Bev = make_step(cE, sE, v12x*invE, v12y*invE, v12z*invE, A[3], A[4], A[5]);

    // odd step 2k+1 (n1' = n2, reuses shared normals)
    float sphO = (mox*n3x+moy*n3y+moz*n3z) * rsqrtf(Lmo*L3);
    float cphO = (n2x*n3x+n2y*n3y+n2z*n3z) * rsqrtf(L2*L3);
    { const float rn = rsqrtf(sphO*sphO + cphO*cphO); sphO *= rn; cphO *= rn; }
    float sthO, cthO; sincosf(th2.y, &sthO, &cthO);
    const float cO = cthO*cphO - sthO*sphO;
    const float sO_ = sthO*cphO + cthO*sphO;
    const float LjkO = v23x*v23x+v23y*v23y+v23z*v23z;
    const float invO = rsqrtf(fmaxf(LjkO, 1e-24f));
    Aff Bod = make_step(cO, sO_, v23x*invO, v23y*invO, v23z*invO, A[6], A[7], A[8]);

    Aff S = aff_compose(Bev, Bod);   // C_k = B_{2k}∘B_{2k+1}

    // ---- wave-inclusive scan: S -> P_{2k+1} ----
    #pragma unroll
    for (int off = 1; off < 64; off <<= 1) {
        Aff Q; SHFL_AFF_UP(Q, S, off);
        if (lane >= off) S = aff_compose(Q, S);
    }
    Aff E; SHFL_AFF_UP(E, S, 1);
    if (lane == 0) { E.qw = 1.f; E.qx = E.qy = E.qz = 0.f; E.tx = E.ty = E.tz = 0.f; }
    Aff Pe = aff_compose(E, Bev);    // P_{2k}
    qnorm(Pe); qnorm(S);

    // ---- emit head atoms into this wave's sO slice ----
    {
        float ox, oy, oz;
        float* op = &sO[wid][lane * 6 + 9];
        qrot(Pe.qw, Pe.qx, Pe.qy, Pe.qz, A[9], A[10], A[11], ox, oy, oz);
        op[0] = ox + Pe.tx; op[1] = oy + Pe.ty; op[2] = oz + Pe.tz;
        qrot(S.qw, S.qx, S.qy, S.qz, A[12], A[13], A[14], ox, oy, oz);
        op[3] = ox + S.tx;  op[4] = oy + S.ty;  op[5] = oz + S.tz;
    }
    if (lane < 9) sO[wid][lane] = sA[wid][lane];   // atoms 0..2 never move
    if (lane == 63) {                               // atom 131 = P_127(pos0[131])
        float ox, oy, oz;
        qrot(S.qw, S.qx, S.qy, S.qz, sA[wid][393], sA[wid][394], sA[wid][395], ox, oy, oz);
        sO[wid][393] = ox + S.tx; sO[wid][394] = oy + S.ty; sO[wid][395] = oz + S.tz;
    }

    // ---- F = P_127 broadcast from lane 63 (register-only) ----
    Aff F;
    F.qw = __shfl(S.qw, 63, 64); F.qx = __shfl(S.qx, 63, 64);
    F.qy = __shfl(S.qy, 63, 64); F.qz = __shfl(S.qz, 63, 64);
    F.tx = __shfl(S.tx, 63, 64); F.ty = __shfl(S.ty, 63, 64);
    F.tz = __shfl(S.tz, 63, 64);
    const float f00 = 1.f - 2.f*(F.qy*F.qy + F.qz*F.qz);
    const float f01 = 2.f*(F.qx*F.qy - F.qw*F.qz);
    const float f02 = 2.f*(F.qx*F.qz + F.qw*F.qy);
    const float f10 = 2.f*(F.qx*F.qy + F.qw*F.qz);
    const float f11 = 1.f - 2.f*(F.qx*F.qx + F.qz*F.qz);
    const float f12 = 2.f*(F.qy*F.qz - F.qw*F.qx);
    const float f20 = 2.f*(F.qx*F.qz - F.qw*F.qy);
    const float f21 = 2.f*(F.qy*F.qz + F.qw*F.qx);
    const float f22 = 1.f - 2.f*(F.qx*F.qx + F.qy*F.qy);

    // ---- store head (99 float4 from this wave's sO) ----
    const float4* sO4 = (const float4*)sO[wid];
    ob4[lane] = sO4[lane];
    if (lane < 35) ob4[64 + lane] = sO4[64 + lane];

    // ---- tail: 95 f4-triples (atoms 132..511), data already in registers ----
    #define TAIL_EMIT(b, va, vb, vc)                                          \
    do {                                                                      \
        const float x0=va.x, y0=va.y, z0=va.z;                                \
        const float x1=va.w, y1=vb.x, z1=vb.y;                                \
        const float x2=vb.z, y2=vb.w, z2=vc.x;                                \
        const float x3=vc.y, y3=vc.z, z3=vc.w;                                \
        float4 o0, o1, o2;                                                    \
        o0.x = f00*x0+f01*y0+f02*z0+F.tx; o0.y = f10*x0+f11*y0+f12*z0+F.ty;   \
        o0.z = f20*x0+f21*y0+f22*z0+F.tz; o0.w = f00*x1+f01*y1+f02*z1+F.tx;   \
        o1.x = f10*x1+f11*y1+f12*z1+F.ty; o1.y = f20*x1+f21*y1+f22*z1+F.tz;   \
        o1.z = f00*x2+f01*y2+f02*z2+F.tx; o1.w = f10*x2+f11*y2+f12*z2+F.ty;   \
        o2.x = f20*x2+f21*y2+f22*z2+F.tz; o2.y = f00*x3+f01*y3+f02*z3+F.tx;   \
        o2.z = f10*x3+f11*y3+f12*z3+F.ty; o2.w = f20*x3+f21*y3+f22*z3+F.tz;   \
        ob4[(b)] = o0; ob4[(b)+1] = o1; ob4[(b)+2] = o2;                      \
    } while (0)

    TAIL_EMIT(99 + 3*lane, Ta0, Ta1, Ta2);
    if (hasB) TAIL_EMIT(99 + 3*(64 + lane), Tb0, Tb1, Tb2);
    #undef TAIL_EMIT
}

extern "C" void kernel_launch(void* const* d_in, const int* in_sizes, int n_in,
                              void* d_out, int out_size, void* d_ws, size_t ws_size,
                              hipStream_t stream) {
    const float* theta = (const float*)d_in[0];  // input (N,K) fp32
    const float* pos0  = (const float*)d_in[1];  // pos0 (N,M,3) fp32
    float* out = (float*)d_out;                  // (N,M,3) fp32
    dihedral_fused_kernel<<<NMOL / MPW, TPB, 0, stream>>>(theta, pos0, out);
}